// Round 4
// baseline (1382.746 us; speedup 1.0000x reference)
//
#include <hip/hip_runtime.h>
#include <hip/hip_bf16.h>

#define N_DIM 4096
#define FT_DIM 512
#define H_DIM 4
#define OUT_LD (H_DIM * N_DIM)  // 16384
#define NTILES 128               // K-tiles of 32

typedef __attribute__((ext_vector_type(8))) __bf16 bf16x8;
typedef __attribute__((ext_vector_type(4))) float f32x4;
typedef unsigned int u32;
typedef unsigned short u16;

__device__ inline float bf2f(u16 u) {
    u32 x = ((u32)u) << 16;
    return __uint_as_float(x);
}
// round-to-nearest-even f32 -> bf16 bits
__device__ inline u16 f2bf_rn(float f) {
    u32 x = __float_as_uint(f);
    u32 r = x + 0x7fffu + ((x >> 16) & 1u);
    return (u16)(r >> 16);
}

__device__ inline void gload16(const void* g, void* l) {
    __builtin_amdgcn_global_load_lds(
        (const __attribute__((address_space(1))) u32*)g,
        (__attribute__((address_space(3))) u32*)l, 16, 0, 0);
}

__device__ inline u32 lds_addr(const void* p) {
    return (u32)(size_t)(const __attribute__((address_space(3))) void*)p;
}

__device__ inline bf16x8 dsr128(u32 addr) {
    bf16x8 d;
    asm volatile("ds_read_b128 %0, %1" : "=v"(d) : "v"(addr));
    return d;
}

// ---------------------------------------------------------------------------
// Kernel 1: w[h][n] = b[h] + sum_f W[h][f] * ft[f][n]
// ---------------------------------------------------------------------------
__global__ __launch_bounds__(256) void wproj_kernel(
    const float* __restrict__ ft, const float* __restrict__ W,
    const float* __restrict__ bvec, float* __restrict__ wout) {
    int n = blockIdx.x * 256 + threadIdx.x;
    float a0 = 0.f, a1 = 0.f, a2 = 0.f, a3 = 0.f;
#pragma unroll 8
    for (int f = 0; f < FT_DIM; ++f) {
        float v = ft[(size_t)f * N_DIM + n];
        a0 = fmaf(W[0 * FT_DIM + f], v, a0);
        a1 = fmaf(W[1 * FT_DIM + f], v, a1);
        a2 = fmaf(W[2 * FT_DIM + f], v, a2);
        a3 = fmaf(W[3 * FT_DIM + f], v, a3);
    }
    wout[0 * N_DIM + n] = a0 + bvec[0];
    wout[1 * N_DIM + n] = a1 + bvec[1];
    wout[2 * N_DIM + n] = a2 + bvec[2];
    wout[3 * N_DIM + n] = a3 + bvec[3];
}

// ---------------------------------------------------------------------------
// Kernel 2: one block per row i; loops all 4 heads, bias row in registers.
// Emits split-precision bf16: hi = bf16(a), lo = bf16(a - hi).
// ---------------------------------------------------------------------------
__global__ __launch_bounds__(256) void softmax_split_kernel(
    const float* __restrict__ w, const float* __restrict__ bias,
    u16* __restrict__ ahi, u16* __restrict__ alo) {
    const int i = blockIdx.x;
    const int t = threadIdx.x;
    __shared__ float red[8];

    float bj[16];
    const float4* b4 = (const float4*)(bias + (size_t)i * N_DIM);
#pragma unroll
    for (int c = 0; c < 4; ++c) {
        float4 v = b4[t + 256 * c];
        bj[c * 4 + 0] = v.x;
        bj[c * 4 + 1] = v.y;
        bj[c * 4 + 2] = v.z;
        bj[c * 4 + 3] = v.w;
    }

    for (int h = 0; h < H_DIM; ++h) {
        __syncthreads();
        const float wi = w[h * N_DIM + i];
        const float4* w4 = (const float4*)(w + h * N_DIM);

        float l[16];
        float m = -1e30f;
#pragma unroll
        for (int c = 0; c < 4; ++c) {
            float4 wj = w4[t + 256 * c];
            float x;
            x = wi + wj.x; x = (x >= 0.f) ? x : 0.2f * x; x += bj[c * 4 + 0]; l[c * 4 + 0] = x;
            x = wi + wj.y; x = (x >= 0.f) ? x : 0.2f * x; x += bj[c * 4 + 1]; l[c * 4 + 1] = x;
            x = wi + wj.z; x = (x >= 0.f) ? x : 0.2f * x; x += bj[c * 4 + 2]; l[c * 4 + 2] = x;
            x = wi + wj.w; x = (x >= 0.f) ? x : 0.2f * x; x += bj[c * 4 + 3]; l[c * 4 + 3] = x;
            m = fmaxf(m, fmaxf(fmaxf(l[c * 4 + 0], l[c * 4 + 1]),
                               fmaxf(l[c * 4 + 2], l[c * 4 + 3])));
        }
#pragma unroll
        for (int o = 32; o > 0; o >>= 1) m = fmaxf(m, __shfl_xor(m, o, 64));
        if ((t & 63) == 0) red[t >> 6] = m;
        __syncthreads();
        m = fmaxf(fmaxf(red[0], red[1]), fmaxf(red[2], red[3]));

        float p[16];
        float s = 0.f;
#pragma unroll
        for (int k = 0; k < 16; ++k) {
            float e = __expf(l[k] - m);
            p[k] = e;
            s += e;
        }
#pragma unroll
        for (int o = 32; o > 0; o >>= 1) s += __shfl_xor(s, o, 64);
        if ((t & 63) == 0) red[4 + (t >> 6)] = s;
        __syncthreads();
        s = (red[4] + red[5]) + (red[6] + red[7]);
        float inv = 1.0f / s;

        u16* hrow = ahi + ((size_t)(h * N_DIM + i)) * N_DIM;
        u16* lrow = alo + ((size_t)(h * N_DIM + i)) * N_DIM;
#pragma unroll
        for (int c = 0; c < 4; ++c) {
            int j0 = (t + 256 * c) * 4;
            ushort4 hv, lv;
            float av;
            av = p[c * 4 + 0] * inv; hv.x = f2bf_rn(av); lv.x = f2bf_rn(av - bf2f(hv.x));
            av = p[c * 4 + 1] * inv; hv.y = f2bf_rn(av); lv.y = f2bf_rn(av - bf2f(hv.y));
            av = p[c * 4 + 2] * inv; hv.z = f2bf_rn(av); lv.z = f2bf_rn(av - bf2f(hv.z));
            av = p[c * 4 + 3] * inv; hv.w = f2bf_rn(av); lv.w = f2bf_rn(av - bf2f(hv.w));
            *(ushort4*)(hrow + j0) = hv;
            *(ushort4*)(lrow + j0) = lv;
        }
    }
}

// ---------------------------------------------------------------------------
// Kernel 3 (MFMA, phase-pipelined): per head, t = a a^T via split bf16:
//   out_IK = U_I U_K^T + U_I L_K^T + L_I U_K^T
// 256x256 tile pair (triangular 16x16 grid), BK=32, 8 waves (2x4), wave tile
// 128x64. LDS: 2 x 64 KB buffers, 4 panels each [256 rows][32 cols] bf16.
// Per K-tile: 4 phases {ds_read frags | stage next tile | barrier |
// lgkmcnt(0) | setprio | 24 MFMA | barrier}; boundary vmcnt(0) is issued
// 3 phases after the prefetch loads (latency covered by MFMA).
// ---------------------------------------------------------------------------
__global__ __launch_bounds__(512, 2) void aat_mfma_kernel(
    const u16* __restrict__ Ahi, const u16* __restrict__ Alo,
    float* __restrict__ out) {
    // XCD-chunked swizzle: 136 = 8 * 17 (exactly divisible -> bijective)
    const int bx = blockIdx.x;
    const int lin = (bx & 7) * 17 + (bx >> 3);
    // triangular decode: lin -> (tI, tK), tK >= tI, 16x16 tiles
    int idx = lin, tI = 0, base = 0;
    while (idx >= base + (16 - tI)) { base += (16 - tI); ++tI; }
    const int tK = tI + (idx - base);
    const int h = blockIdx.y;

    const int t = threadIdx.x;
    const int l = t & 63;
    const int wv = t >> 6;   // 0..7
    const int wr = wv >> 2;  // 0..1 : 128-row half
    const int wc = wv & 3;   // 0..3 : 64-col quarter
    const int lr = l & 15, c16 = l >> 4;

    __shared__ __align__(16) unsigned char smem[131072];  // 2 x 64 KB
    const u32 sbase = lds_addr(smem);

    const size_t headoff = (size_t)h * N_DIM * N_DIM;
    const char* baseP[4];
    baseP[0] = (const char*)(Ahi + headoff + (size_t)(tI * 256) * N_DIM);  // U_I
    baseP[1] = (const char*)(Alo + headoff + (size_t)(tI * 256) * N_DIM);  // L_I
    baseP[2] = (const char*)(Ahi + headoff + (size_t)(tK * 256) * N_DIM);  // U_K
    baseP[3] = (const char*)(Alo + headoff + (size_t)(tK * 256) * N_DIM);  // L_K

    // staging: thread covers chunks {t, t+512} within each 1024-chunk panel
    u32 gsoff[2];
#pragma unroll
    for (int s2 = 0; s2 < 2; ++s2) {
        int pc = t + 512 * s2;  // panel-chunk 0..1023
        int row = pc >> 2;      // 0..255
        int cc = (pc & 3) ^ ((row >> 1) & 3);  // inverse-swizzled SOURCE
        gsoff[s2] = (u32)row * (N_DIM * 2) + (u32)cc * 16;
    }
    const u32 lbase = (u32)t * 16;  // + j*8192 + buf*65536 (linear LDS dest)

    // fragment read addresses for buffer 0 (swizzled READ)
    u32 oAU[8], oAL[8], oBU[4], oBL[4];
#pragma unroll
    for (int mi = 0; mi < 8; ++mi) {
        int r = wr * 128 + mi * 16 + lr;
        u32 o = (u32)r * 64 + (u32)((c16 ^ ((r >> 1) & 3)) * 16);
        oAU[mi] = sbase + o;
        oAL[mi] = sbase + 16384 + o;
    }
#pragma unroll
    for (int ni = 0; ni < 4; ++ni) {
        int r = wc * 64 + ni * 16 + lr;
        u32 o = (u32)r * 64 + (u32)((c16 ^ ((r >> 1) & 3)) * 16);
        oBU[ni] = sbase + 32768 + o;
        oBL[ni] = sbase + 49152 + o;
    }

    f32x4 acc[8][4];
#pragma unroll
    for (int mi = 0; mi < 8; ++mi)
#pragma unroll
        for (int ni = 0; ni < 4; ++ni) acc[mi][ni] = (f32x4){0.f, 0.f, 0.f, 0.f};

    // prologue: stage tile 0 into buffer 0, drain, align
#pragma unroll
    for (int j = 0; j < 8; ++j)
        gload16(baseP[j >> 1] + gsoff[j & 1], smem + (lbase + j * 8192));
    asm volatile("s_waitcnt vmcnt(0)" ::: "memory");
    __builtin_amdgcn_sched_barrier(0);
    __builtin_amdgcn_s_barrier();

    for (int tk = 0; tk < NTILES; ++tk) {
        const u32 curoff = (u32)(tk & 1) << 16;
        const u32 nxtoff = curoff ^ 65536u;
        bf16x8 bU[4], bL[4];
#pragma unroll
        for (int q = 0; q < 4; ++q) {
            // ---- phase q: ds-reads ----
            if (q == 0) {
#pragma unroll
                for (int ni = 0; ni < 4; ++ni) {
                    bU[ni] = dsr128(oBU[ni] + curoff);
                    bL[ni] = dsr128(oBL[ni] + curoff);
                }
            }
            bf16x8 aU0 = dsr128(oAU[2 * q + 0] + curoff);
            bf16x8 aU1 = dsr128(oAU[2 * q + 1] + curoff);
            bf16x8 aL0 = dsr128(oAL[2 * q + 0] + curoff);
            bf16x8 aL1 = dsr128(oAL[2 * q + 1] + curoff);
            // ---- phase 1 only: issue next-tile staging (1 tile ahead) ----
            if (q == 0 && tk < NTILES - 1) {
                const u32 ktb = (u32)(tk + 1) * 64;
#pragma unroll
                for (int j = 0; j < 8; ++j)
                    gload16(baseP[j >> 1] + ktb + gsoff[j & 1],
                            smem + (nxtoff + lbase + j * 8192));
            }
            __builtin_amdgcn_s_barrier();
            asm volatile("s_waitcnt lgkmcnt(0)" ::: "memory");
            __builtin_amdgcn_sched_barrier(0);
            __builtin_amdgcn_s_setprio(1);
#pragma unroll
            for (int m2 = 0; m2 < 2; ++m2) {
                const bf16x8 au = m2 ? aU1 : aU0;
                const bf16x8 al = m2 ? aL1 : aL0;
#pragma unroll
                for (int ni = 0; ni < 4; ++ni) {
                    acc[2 * q + m2][ni] = __builtin_amdgcn_mfma_f32_16x16x32_bf16(
                        au, bU[ni], acc[2 * q + m2][ni], 0, 0, 0);
                    acc[2 * q + m2][ni] = __builtin_amdgcn_mfma_f32_16x16x32_bf16(
                        au, bL[ni], acc[2 * q + m2][ni], 0, 0, 0);
                    acc[2 * q + m2][ni] = __builtin_amdgcn_mfma_f32_16x16x32_bf16(
                        al, bU[ni], acc[2 * q + m2][ni], 0, 0, 0);
                }
            }
            __builtin_amdgcn_s_setprio(0);
            if (q == 3) {  // next-tile staging done? (issued 3 phases ago)
                asm volatile("s_waitcnt vmcnt(0)" ::: "memory");
                __builtin_amdgcn_sched_barrier(0);
            }
            __builtin_amdgcn_s_barrier();
        }
    }

    // C/D layout (m89): col = lane&15, row = (lane>>4)*4 + reg
    float* oh = out + (size_t)h * N_DIM;
    const int r0b = tI * 256 + wr * 128;
    const int c0b = tK * 256 + wc * 64;
#pragma unroll
    for (int mi = 0; mi < 8; ++mi)
#pragma unroll
        for (int ni = 0; ni < 4; ++ni) {
            int r0 = r0b + mi * 16 + c16 * 4;
            int cc0 = c0b + ni * 16 + lr;
            oh[(size_t)(r0 + 0) * OUT_LD + cc0] = acc[mi][ni][0];
            oh[(size_t)(r0 + 1) * OUT_LD + cc0] = acc[mi][ni][1];
            oh[(size_t)(r0 + 2) * OUT_LD + cc0] = acc[mi][ni][2];
            oh[(size_t)(r0 + 3) * OUT_LD + cc0] = acc[mi][ni][3];
        }

    if (tI != tK) {  // mirror store: out[k][i] = out[i][k]
#pragma unroll
        for (int mi = 0; mi < 8; ++mi)
#pragma unroll
            for (int ni = 0; ni < 4; ++ni) {
                int rm = c0b + ni * 16 + lr;
                int cm = r0b + mi * 16 + c16 * 4;
                *(f32x4*)(oh + (size_t)rm * OUT_LD + cm) = acc[mi][ni];
            }
    }
}

// ---------------------------------------------------------------------------
extern "C" void kernel_launch(void* const* d_in, const int* in_sizes, int n_in,
                              void* d_out, int out_size, void* d_ws,
                              size_t ws_size, hipStream_t stream) {
    const float* ft = (const float*)d_in[0];    // (1, 512, 4096)
    const float* bias = (const float*)d_in[1];  // (1, 4096, 4096)
    const float* W = (const float*)d_in[2];     // (4, 512)
    const float* bvec = (const float*)d_in[3];  // (4,)
    float* out = (float*)d_out;                 // (1, 4096, 16384)

    float* wbuf = (float*)d_ws;  // 64 KB
    const size_t a_elems = (size_t)H_DIM * N_DIM * N_DIM;
    u16* ahi = (u16*)((char*)d_ws + 65536);                // 128 MB
    u16* alo = (u16*)((char*)d_ws + 65536 + a_elems * 2);  // 128 MB

    wproj_kernel<<<dim3(16), dim3(256), 0, stream>>>(ft, W, bvec, wbuf);
    softmax_split_kernel<<<dim3(N_DIM), dim3(256), 0, stream>>>(wbuf, bias,
                                                                ahi, alo);
    const int ntiles = 16 * 17 / 2;  // 136 upper-triangular 256x256 tile pairs
    aat_mfma_kernel<<<dim3(ntiles, H_DIM), dim3(512), 0, stream>>>(ahi, alo,
                                                                   out);
}